// Round 3
// baseline (16757.652 us; speedup 1.0000x reference)
//
#include <hip/hip_runtime.h>
#include <hip/hip_fp16.h>

typedef _Float16 f16x8 __attribute__((ext_vector_type(8)));
typedef float f32x4 __attribute__((ext_vector_type(4)));

namespace {
constexpr int BB = 32;    // batch
constexpr int SS = 512;   // seq len
constexpr int HH = 512;   // hidden
constexpr int G4 = 2048;  // 4*H gates
constexpr int NWGR = 16;  // workgroups per direction in recurrence (1024 thr each)
constexpr int FPAD = 16;  // flag padding: 16 ints = 64B line per flag
}

// ---------------- utility kernels ----------------
__global__ void k_zero(int* __restrict__ p, int n) {
  int i = blockIdx.x * blockDim.x + threadIdx.x;
  if (i < n) p[i] = 0;
}

__global__ void k_cvt(const float* __restrict__ s, _Float16* __restrict__ d, int n) {
  int i = blockIdx.x * blockDim.x + threadIdx.x;
  int stride = gridDim.x * blockDim.x;
  for (; i < n; i += stride) d[i] = (_Float16)s[i];
}

// ---------------- input-projection GEMM (unchanged from R2) ----------------
__global__ __launch_bounds__(256) void k_gemm(
    const _Float16* __restrict__ Ain,  // [16384][K]
    const _Float16* __restrict__ W,    // [2][2048][K]
    const float* __restrict__ bih0, const float* __restrict__ bhh0,
    const float* __restrict__ bih1, const float* __restrict__ bhh1,
    _Float16* __restrict__ gx,         // [2][512][32][2048]
    int K) {
  __shared__ _Float16 As[128][40];
  __shared__ _Float16 Bs[128][40];
  const int tid = threadIdx.x;
  const int lane = tid & 63, wave = tid >> 6;
  const int dir = blockIdx.z;
  const int r0 = blockIdx.x * 128;
  const int n0 = blockIdx.y * 128;
  const _Float16* Wd = W + (size_t)dir * G4 * K;
  const float* bi = dir ? bih1 : bih0;
  const float* bh = dir ? bhh1 : bhh0;
  const int mw = wave & 1, nw = wave >> 1;

  f32x4 acc[4][4];
#pragma unroll
  for (int a = 0; a < 4; ++a)
#pragma unroll
    for (int b = 0; b < 4; ++b) acc[a][b] = (f32x4){0.f, 0.f, 0.f, 0.f};

  const int c1 = tid, c2 = tid + 256;
  const int ar1 = c1 >> 2, ak1 = (c1 & 3) * 8;
  const int ar2 = c2 >> 2, ak2 = (c2 & 3) * 8;
  const int fr = lane & 15, fq = (lane >> 4) * 8;

  const int nstage = K >> 5;
  for (int ks = 0; ks < nstage; ++ks) {
    const int k0 = ks << 5;
    *(f16x8*)&As[ar1][ak1] = *(const f16x8*)&Ain[(size_t)(r0 + ar1) * K + k0 + ak1];
    *(f16x8*)&As[ar2][ak2] = *(const f16x8*)&Ain[(size_t)(r0 + ar2) * K + k0 + ak2];
    *(f16x8*)&Bs[ar1][ak1] = *(const f16x8*)&Wd[(size_t)(n0 + ar1) * K + k0 + ak1];
    *(f16x8*)&Bs[ar2][ak2] = *(const f16x8*)&Wd[(size_t)(n0 + ar2) * K + k0 + ak2];
    __syncthreads();
    f16x8 af[4], bf[4];
#pragma unroll
    for (int mt = 0; mt < 4; ++mt) af[mt] = *(const f16x8*)&As[mw * 64 + mt * 16 + fr][fq];
#pragma unroll
    for (int nt = 0; nt < 4; ++nt) bf[nt] = *(const f16x8*)&Bs[nw * 64 + nt * 16 + fr][fq];
#pragma unroll
    for (int mt = 0; mt < 4; ++mt)
#pragma unroll
      for (int nt = 0; nt < 4; ++nt)
        acc[mt][nt] = __builtin_amdgcn_mfma_f32_16x16x32_f16(af[mt], bf[nt], acc[mt][nt], 0, 0, 0);
    __syncthreads();
  }

  const int q4 = (lane >> 4) * 4;
#pragma unroll
  for (int nt = 0; nt < 4; ++nt) {
    const int col = n0 + nw * 64 + nt * 16 + fr;
    const float bsum = bi[col] + bh[col];
#pragma unroll
    for (int mt = 0; mt < 4; ++mt) {
#pragma unroll
      for (int q = 0; q < 4; ++q) {
        const int r = r0 + mw * 64 + mt * 16 + q4 + q;
        const int b = r >> 9, t = r & 511;
        gx[(((size_t)dir * SS + t) * BB + b) * G4 + col] = (_Float16)(acc[mt][nt][q] + bsum);
      }
    }
  }
}

// ---------------- fast activations ----------------
__device__ __forceinline__ float sigmoid_fast(float x) {
  return __fdividef(1.f, 1.f + __expf(-x));
}
__device__ __forceinline__ float tanh_fast(float x) {
  const float e = __expf(2.f * x);
  return 1.f - __fdividef(2.f, e + 1.f);
}

// ---------------- recurrence (cooperative, 32 WGs = 16 x 1024thr per direction) ----
// Each WG owns 32 hidden units (all 4 gates = 128 gate rows) for one direction;
// Whh rows live in registers (16 B-frags/wave). Per step: poll 16 peer flags
// (self substituted locally), pull h(t-1) via coherent 8B loads, 16 MFMAs/wave,
// LDS gate exchange, pointwise, pack h into 8B write-through stores, signal.
// No agent fences on the critical path: barrier vmcnt-drain + write-through
// stores give release semantics (same mechanism validated in R1/R2).
__global__ __launch_bounds__(1024) void k_recur(
    const _Float16* __restrict__ gx,   // [2][512][32][2048]
    const _Float16* __restrict__ Whh,  // [2][2048][512] fp16, this layer
    _Float16* __restrict__ y,          // [32][512][1024] fp16 layer output
    float* __restrict__ outf,          // nullptr, or [32][512][1024] fp32 (layer 1)
    int* __restrict__ flags) {         // [2][NWGR*FPAD]
  const int tid = threadIdx.x;
  const int lane = tid & 63, wave = tid >> 6;   // wave 0..15
  const int wg = blockIdx.x & (NWGR - 1);
  const int dir = blockIdx.x >> 4;
  const int m = wave & 1, nt = wave >> 1;       // m: batch half, nt: 0..7
  const int g = nt >> 1, uh = nt & 1;           // gate id, unit-half

  __shared__ float gates_s[4][32][34];          // [gate][batch][unit] (+2 pad)
  __shared__ __align__(16) unsigned short h_s[32][32];

  const int c = lane & 15;
  const int quad8 = (lane >> 4) * 8;
  // B-frag row: gate-row = g*512 + wg*32 + uh*16 + c   (each row held once per m-half)
  const int grow = g * HH + wg * 32 + uh * 16 + c;
  const _Float16* Wd = Whh + ((size_t)dir * G4 + grow) * HH;
  f16x8 bfrag[16];
#pragma unroll
  for (int kk = 0; kk < 16; ++kk) bfrag[kk] = *(const f16x8*)&Wd[kk * 32 + quad8];

  const int tb = tid >> 5, tu = tid & 31;  // this thread owns (batch tb, unit tu)
  const int ucol = wg * 32 + tu;           // unit in [0,512)
  float cstate = 0.f;

  const _Float16* gxd = gx + (size_t)dir * SS * BB * G4;
  int* fl = flags + dir * (NWGR * FPAD);
  const int pollidx = lane & 15;

  struct U2 { unsigned long long a, b; };

  for (int s = 0; s < SS; ++s) {
    const int t = dir ? (SS - 1 - s) : s;
    const int tprev = dir ? (t + 1) : (t - 1);

    // gx prefetch (read-only, L2-cacheable plain loads; overlaps the wait)
    const _Float16* gq = gxd + ((size_t)t * BB + tb) * G4 + ucol;
    const float gxi = (float)gq[0];
    const float gxf = (float)gq[HH];
    const float gxg = (float)gq[2 * HH];
    const float gxo = (float)gq[3 * HH];

    f32x4 acc = (f32x4){0.f, 0.f, 0.f, 0.f};
    if (s > 0) {
      // every wave polls independently; own WG's flag substituted locally
      while (true) {
        const int v = (pollidx == wg)
                          ? s
                          : __hip_atomic_load(&fl[pollidx * FPAD], __ATOMIC_RELAXED,
                                              __HIP_MEMORY_SCOPE_AGENT);
        if (__all(v >= s)) break;
      }
      __atomic_signal_fence(__ATOMIC_ACQUIRE);
      // A-frags of h(t_prev): batch row = m*16 + c, coherent 8B loads
      const _Float16* hrow = y + ((size_t)(m * 16 + c) * SS + tprev) * 1024 + dir * HH;
      const unsigned long long* h64 = (const unsigned long long*)hrow;
      const int qo = quad8 >> 2;
      f16x8 af[16];
#pragma unroll
      for (int kk = 0; kk < 16; ++kk) {
        U2 u;
        u.a = __hip_atomic_load(h64 + kk * 8 + qo, __ATOMIC_RELAXED, __HIP_MEMORY_SCOPE_AGENT);
        u.b = __hip_atomic_load(h64 + kk * 8 + qo + 1, __ATOMIC_RELAXED, __HIP_MEMORY_SCOPE_AGENT);
        af[kk] = __builtin_bit_cast(f16x8, u);
      }
      f32x4 a0 = (f32x4){0.f, 0.f, 0.f, 0.f}, a1 = a0, a2 = a0, a3 = a0;
#pragma unroll
      for (int kk = 0; kk < 16; kk += 4) {
        a0 = __builtin_amdgcn_mfma_f32_16x16x32_f16(af[kk], bfrag[kk], a0, 0, 0, 0);
        a1 = __builtin_amdgcn_mfma_f32_16x16x32_f16(af[kk + 1], bfrag[kk + 1], a1, 0, 0, 0);
        a2 = __builtin_amdgcn_mfma_f32_16x16x32_f16(af[kk + 2], bfrag[kk + 2], a2, 0, 0, 0);
        a3 = __builtin_amdgcn_mfma_f32_16x16x32_f16(af[kk + 3], bfrag[kk + 3], a3, 0, 0, 0);
      }
      acc = (a0 + a1) + (a2 + a3);
    }
    // scatter: D col = lane&15 (unit), row = (lane>>4)*4+q (batch)
#pragma unroll
    for (int q = 0; q < 4; ++q)
      gates_s[g][m * 16 + (lane >> 4) * 4 + q][uh * 16 + c] = acc[q];
    __syncthreads();  // B2: gate tiles complete

    const float ip = gates_s[0][tb][tu] + gxi;
    const float fp = gates_s[1][tb][tu] + gxf;
    const float gp = gates_s[2][tb][tu] + gxg;
    const float op = gates_s[3][tb][tu] + gxo;
    const float iv = sigmoid_fast(ip);
    const float fv = sigmoid_fast(fp);
    const float gv = tanh_fast(gp);
    const float ov = sigmoid_fast(op);
    cstate = fv * cstate + iv * gv;
    const float hv = ov * tanh_fast(cstate);
    h_s[tb][tu] = __builtin_bit_cast(unsigned short, (_Float16)hv);
    if (outf)  // plain cached store; off the coherence path (kernel-end writeback)
      outf[((size_t)tb * SS + t) * 1024 + dir * HH + ucol] = hv;
    __syncthreads();  // B3: h_s complete

    if (tid < 128) {  // pack: 2x 8B write-through stores per thread (32 rows x 64B)
      const int r = tid >> 2, seg = tid & 3;
      const uint4 hv4 = *(const uint4*)&h_s[r][seg * 8];
      const unsigned long long lo = ((unsigned long long)hv4.y << 32) | hv4.x;
      const unsigned long long hi = ((unsigned long long)hv4.w << 32) | hv4.z;
      unsigned long long* dst =
          (unsigned long long*)(y + ((size_t)r * SS + t) * 1024 + dir * HH + wg * 32 + seg * 8);
      __hip_atomic_store(dst, lo, __ATOMIC_RELAXED, __HIP_MEMORY_SCOPE_AGENT);
      __hip_atomic_store(dst + 1, hi, __ATOMIC_RELAXED, __HIP_MEMORY_SCOPE_AGENT);
    }
    __atomic_signal_fence(__ATOMIC_RELEASE);
    __syncthreads();  // B4: every wave's vmcnt drained before signal
    if (tid == 0)
      __hip_atomic_store(&fl[wg * FPAD], s + 1, __ATOMIC_RELAXED, __HIP_MEMORY_SCOPE_AGENT);
  }
}

// ---------------- launch ----------------
extern "C" void kernel_launch(void* const* d_in, const int* in_sizes, int n_in,
                              void* d_out, int out_size, void* d_ws, size_t ws_size,
                              hipStream_t stream) {
  (void)in_sizes; (void)n_in; (void)out_size; (void)ws_size;
  const float* x = (const float*)d_in[0];
  const float* Wih[4] = {(const float*)d_in[1], (const float*)d_in[5],
                         (const float*)d_in[9], (const float*)d_in[13]};
  const float* Whh[4] = {(const float*)d_in[2], (const float*)d_in[6],
                         (const float*)d_in[10], (const float*)d_in[14]};
  const float* bih[4] = {(const float*)d_in[3], (const float*)d_in[7],
                         (const float*)d_in[11], (const float*)d_in[15]};
  const float* bhh[4] = {(const float*)d_in[4], (const float*)d_in[8],
                         (const float*)d_in[12], (const float*)d_in[16]};

  char* p = (char*)d_ws;
  auto take = [&](size_t bytes) { char* r = p; p += (bytes + 255) & ~(size_t)255; return r; };
  _Float16* x16  = (_Float16*)take((size_t)BB * SS * 512 * 2);
  _Float16* wih0 = (_Float16*)take((size_t)2 * G4 * 512 * 2);
  _Float16* wih1 = (_Float16*)take((size_t)2 * G4 * 1024 * 2);
  _Float16* whh16 = (_Float16*)take((size_t)4 * G4 * 512 * 2);
  _Float16* gx   = (_Float16*)take((size_t)2 * SS * BB * G4 * 2);
  _Float16* y0   = (_Float16*)take((size_t)BB * SS * 1024 * 2);
  _Float16* y1   = (_Float16*)take((size_t)BB * SS * 1024 * 2);
  int* flags     = (int*)take((size_t)2 * 2 * NWGR * FPAD * 4);  // 2 layers x 2 dirs

  hipLaunchKernelGGL(k_zero, dim3(4), dim3(256), 0, stream, flags, 2 * 2 * NWGR * FPAD);
  hipLaunchKernelGGL(k_cvt, dim3(512), dim3(256), 0, stream, x, x16, BB * SS * 512);
  hipLaunchKernelGGL(k_cvt, dim3(128), dim3(256), 0, stream, Wih[0], wih0, G4 * 512);
  hipLaunchKernelGGL(k_cvt, dim3(128), dim3(256), 0, stream, Wih[1], wih0 + (size_t)G4 * 512, G4 * 512);
  hipLaunchKernelGGL(k_cvt, dim3(256), dim3(256), 0, stream, Wih[2], wih1, G4 * 1024);
  hipLaunchKernelGGL(k_cvt, dim3(256), dim3(256), 0, stream, Wih[3], wih1 + (size_t)G4 * 1024, G4 * 1024);
  for (int i = 0; i < 4; ++i)
    hipLaunchKernelGGL(k_cvt, dim3(128), dim3(256), 0, stream, Whh[i],
                       whh16 + (size_t)i * G4 * 512, G4 * 512);

  // layer 0
  hipLaunchKernelGGL(k_gemm, dim3(128, 16, 2), dim3(256), 0, stream,
                     x16, wih0, bih[0], bhh[0], bih[1], bhh[1], gx, 512);
  {
    const _Float16* gxp = gx; const _Float16* whhp = whh16;
    _Float16* yp = y0; float* op = nullptr; int* cp = flags;
    void* args[] = {&gxp, &whhp, &yp, &op, &cp};
    hipLaunchCooperativeKernel((const void*)k_recur, dim3(2 * NWGR), dim3(1024), args, 0, stream);
  }
  // layer 1
  hipLaunchKernelGGL(k_gemm, dim3(128, 16, 2), dim3(256), 0, stream,
                     y0, wih1, bih[2], bhh[2], bih[3], bhh[3], gx, 1024);
  {
    const _Float16* gxp = gx; const _Float16* whhp = whh16 + (size_t)2 * G4 * 512;
    _Float16* yp = y1; float* op = (float*)d_out; int* cp = flags + 2 * NWGR * FPAD;
    void* args[] = {&gxp, &whhp, &yp, &op, &cp};
    hipLaunchCooperativeKernel((const void*)k_recur, dim3(2 * NWGR), dim3(1024), args, 0, stream);
  }
}

// Round 4
// 4316.252 us; speedup vs baseline: 3.8825x; 3.8825x over previous
//
#include <hip/hip_runtime.h>
#include <hip/hip_fp16.h>

typedef _Float16 f16x8 __attribute__((ext_vector_type(8)));
typedef float f32x4 __attribute__((ext_vector_type(4)));

namespace {
constexpr int BB = 32;    // batch
constexpr int SS = 512;   // seq len
constexpr int HH = 512;   // hidden
constexpr int G4 = 2048;  // 4*H gates
constexpr int NWGR = 32;  // workgroups per direction in recurrence (512 thr each)
constexpr int FPAD = 16;  // flag padding: 16 ints = 64B line per flag
}

// ---------------- utility kernels ----------------
__global__ void k_zero(int* __restrict__ p, int n) {
  int i = blockIdx.x * blockDim.x + threadIdx.x;
  if (i < n) p[i] = 0;
}

__global__ void k_cvt(const float* __restrict__ s, _Float16* __restrict__ d, int n) {
  int i = blockIdx.x * blockDim.x + threadIdx.x;
  int stride = gridDim.x * blockDim.x;
  for (; i < n; i += stride) d[i] = (_Float16)s[i];
}

// ---------------- input-projection GEMM (unchanged) ----------------
__global__ __launch_bounds__(256) void k_gemm(
    const _Float16* __restrict__ Ain,  // [16384][K]
    const _Float16* __restrict__ W,    // [2][2048][K]
    const float* __restrict__ bih0, const float* __restrict__ bhh0,
    const float* __restrict__ bih1, const float* __restrict__ bhh1,
    _Float16* __restrict__ gx,         // [2][512][32][2048]
    int K) {
  __shared__ _Float16 As[128][40];
  __shared__ _Float16 Bs[128][40];
  const int tid = threadIdx.x;
  const int lane = tid & 63, wave = tid >> 6;
  const int dir = blockIdx.z;
  const int r0 = blockIdx.x * 128;
  const int n0 = blockIdx.y * 128;
  const _Float16* Wd = W + (size_t)dir * G4 * K;
  const float* bi = dir ? bih1 : bih0;
  const float* bh = dir ? bhh1 : bhh0;
  const int mw = wave & 1, nw = wave >> 1;

  f32x4 acc[4][4];
#pragma unroll
  for (int a = 0; a < 4; ++a)
#pragma unroll
    for (int b = 0; b < 4; ++b) acc[a][b] = (f32x4){0.f, 0.f, 0.f, 0.f};

  const int c1 = tid, c2 = tid + 256;
  const int ar1 = c1 >> 2, ak1 = (c1 & 3) * 8;
  const int ar2 = c2 >> 2, ak2 = (c2 & 3) * 8;
  const int fr = lane & 15, fq = (lane >> 4) * 8;

  const int nstage = K >> 5;
  for (int ks = 0; ks < nstage; ++ks) {
    const int k0 = ks << 5;
    *(f16x8*)&As[ar1][ak1] = *(const f16x8*)&Ain[(size_t)(r0 + ar1) * K + k0 + ak1];
    *(f16x8*)&As[ar2][ak2] = *(const f16x8*)&Ain[(size_t)(r0 + ar2) * K + k0 + ak2];
    *(f16x8*)&Bs[ar1][ak1] = *(const f16x8*)&Wd[(size_t)(n0 + ar1) * K + k0 + ak1];
    *(f16x8*)&Bs[ar2][ak2] = *(const f16x8*)&Wd[(size_t)(n0 + ar2) * K + k0 + ak2];
    __syncthreads();
    f16x8 af[4], bf[4];
#pragma unroll
    for (int mt = 0; mt < 4; ++mt) af[mt] = *(const f16x8*)&As[mw * 64 + mt * 16 + fr][fq];
#pragma unroll
    for (int nt = 0; nt < 4; ++nt) bf[nt] = *(const f16x8*)&Bs[nw * 64 + nt * 16 + fr][fq];
#pragma unroll
    for (int mt = 0; mt < 4; ++mt)
#pragma unroll
      for (int nt = 0; nt < 4; ++nt)
        acc[mt][nt] = __builtin_amdgcn_mfma_f32_16x16x32_f16(af[mt], bf[nt], acc[mt][nt], 0, 0, 0);
    __syncthreads();
  }

  const int q4 = (lane >> 4) * 4;
#pragma unroll
  for (int nt = 0; nt < 4; ++nt) {
    const int col = n0 + nw * 64 + nt * 16 + fr;
    const float bsum = bi[col] + bh[col];
#pragma unroll
    for (int mt = 0; mt < 4; ++mt) {
#pragma unroll
      for (int q = 0; q < 4; ++q) {
        const int r = r0 + mw * 64 + mt * 16 + q4 + q;
        const int b = r >> 9, t = r & 511;
        gx[(((size_t)dir * SS + t) * BB + b) * G4 + col] = (_Float16)(acc[mt][nt][q] + bsum);
      }
    }
  }
}

// ---------------- fast activations ----------------
__device__ __forceinline__ float sigmoid_fast(float x) {
  return __fdividef(1.f, 1.f + __expf(-x));
}
__device__ __forceinline__ float tanh_fast(float x) {
  const float e = __expf(2.f * x);
  return 1.f - __fdividef(2.f, e + 1.f);
}

// ---------------- recurrence: 64 WGs = 32 x 512thr per direction ----------------
// Each WG owns 16 hidden units (64 gate rows). 8 waves = 2 batch-halves x 4
// K-chunks: every wave loads a DISJOINT 128-wide K-chunk of h(t-1) (64 B/lane,
// zero redundancy: WG reads exactly the 32 KB h payload). Partial gate sums are
// reduced through the LDS gate exchange. Wave 0 polls 32 per-WG flags with
// s_sleep backoff. Whh B-fragments live in registers (64 VGPRs/thread).
__global__ __launch_bounds__(512, 2) void k_recur(
    const _Float16* __restrict__ gx,   // [2][512][32][2048]
    const _Float16* __restrict__ Whh,  // [2][2048][512] fp16, this layer
    _Float16* __restrict__ y,          // [32][512][1024] fp16 layer output
    float* __restrict__ outf,          // nullptr, or [32][512][1024] fp32 (layer 1)
    int* __restrict__ flags) {         // [2][NWGR*FPAD]
  const int tid = threadIdx.x;
  const int lane = tid & 63, wave = tid >> 6;   // wave 0..7
  const int wg = blockIdx.x & (NWGR - 1);
  const int dir = blockIdx.x >> 5;
  const int m = wave & 1, kc = wave >> 1;       // batch half, K chunk

  __shared__ float gp_s[16][32][18];            // [kc*4+gate][batch][unit] partials
  __shared__ __align__(16) unsigned short h_s[32][16];

  const int c = lane & 15;
  const int qd = lane >> 4;
  const int quad8 = qd * 8;

  // B-frags: gate row = g*512 + wg*16 + c, k = kc*128 + kj*32 + quad8
  const _Float16* WdB = Whh + (size_t)dir * G4 * HH;
  f16x8 bfrag[4][4];
#pragma unroll
  for (int g = 0; g < 4; ++g)
#pragma unroll
    for (int kj = 0; kj < 4; ++kj)
      bfrag[g][kj] =
          *(const f16x8*)&WdB[(size_t)(g * HH + wg * 16 + c) * HH + kc * 128 + kj * 32 + quad8];

  const int tb = tid >> 4, tu = tid & 15;  // pointwise ownership (batch, unit)
  float cstate = 0.f;

  const _Float16* gxd = gx + (size_t)dir * SS * BB * G4;
  int* fl = flags + dir * (NWGR * FPAD);

  struct U2 { unsigned long long a, b; };

  for (int s = 0; s < SS; ++s) {
    const int t = dir ? (SS - 1 - s) : s;
    const int tprev = dir ? (t + 1) : (t - 1);

    // gx prefetch (plain cached loads; overlaps the wait)
    const _Float16* gq = gxd + ((size_t)t * BB + tb) * G4 + wg * 16 + tu;
    const float gxi = (float)gq[0];
    const float gxf = (float)gq[HH];
    const float gxg = (float)gq[2 * HH];
    const float gxo = (float)gq[3 * HH];

    f32x4 acc[4];
#pragma unroll
    for (int g = 0; g < 4; ++g) acc[g] = (f32x4){0.f, 0.f, 0.f, 0.f};

    if (s > 0) {
      if (wave == 0) {  // lanes 0..31 poll one flag each, with backoff
        const int pi = lane & 31;
        while (true) {
          int v = s;
          if (lane < 32 && pi != wg)
            v = __hip_atomic_load(&fl[pi * FPAD], __ATOMIC_RELAXED, __HIP_MEMORY_SCOPE_AGENT);
          if (__all(v >= s)) break;
          __builtin_amdgcn_s_sleep(1);
        }
      }
      __syncthreads();  // B1
      __atomic_signal_fence(__ATOMIC_ACQUIRE);
      // A-frags: batch row = m*16 + c, disjoint K chunk per wave (64 B/lane)
      const _Float16* hrow = y + ((size_t)(m * 16 + c) * SS + tprev) * 1024 + dir * HH;
      const unsigned long long* h64 = (const unsigned long long*)hrow;
      f16x8 af[4];
#pragma unroll
      for (int kj = 0; kj < 4; ++kj) {
        const int o = kc * 32 + kj * 8 + qd * 2;
        U2 u;
        u.a = __hip_atomic_load(h64 + o, __ATOMIC_RELAXED, __HIP_MEMORY_SCOPE_AGENT);
        u.b = __hip_atomic_load(h64 + o + 1, __ATOMIC_RELAXED, __HIP_MEMORY_SCOPE_AGENT);
        af[kj] = __builtin_bit_cast(f16x8, u);
      }
#pragma unroll
      for (int kj = 0; kj < 4; ++kj)
#pragma unroll
        for (int g = 0; g < 4; ++g)
          acc[g] = __builtin_amdgcn_mfma_f32_16x16x32_f16(af[kj], bfrag[g][kj], acc[g], 0, 0, 0);
    }
    // scatter partials: D col = lane&15 (gate row within tile), row = qd*4+q (batch)
#pragma unroll
    for (int g = 0; g < 4; ++g)
#pragma unroll
      for (int q = 0; q < 4; ++q) gp_s[kc * 4 + g][m * 16 + qd * 4 + q][c] = acc[g][q];
    __syncthreads();  // B2

    // pointwise: thread (tb, tu) reduces 4 K-chunk partials per gate
    const float ip = gp_s[0][tb][tu] + gp_s[4][tb][tu] + gp_s[8][tb][tu] + gp_s[12][tb][tu] + gxi;
    const float fp = gp_s[1][tb][tu] + gp_s[5][tb][tu] + gp_s[9][tb][tu] + gp_s[13][tb][tu] + gxf;
    const float gp = gp_s[2][tb][tu] + gp_s[6][tb][tu] + gp_s[10][tb][tu] + gp_s[14][tb][tu] + gxg;
    const float op = gp_s[3][tb][tu] + gp_s[7][tb][tu] + gp_s[11][tb][tu] + gp_s[15][tb][tu] + gxo;
    const float iv = sigmoid_fast(ip);
    const float fv = sigmoid_fast(fp);
    const float gv = tanh_fast(gp);
    const float ov = sigmoid_fast(op);
    cstate = fv * cstate + iv * gv;
    const float hv = ov * tanh_fast(cstate);
    h_s[tb][tu] = __builtin_bit_cast(unsigned short, (_Float16)hv);
    if (outf)  // plain cached store; off the coherence path
      outf[((size_t)tb * SS + t) * 1024 + dir * HH + wg * 16 + tu] = hv;
    __syncthreads();  // B3: h_s complete

    if (tid < 128) {  // pack: one 8B write-through store per thread (32 rows x 32B)
      const int r = tid >> 2, seg = tid & 3;
      const unsigned long long hv8 = *(const unsigned long long*)&h_s[r][seg * 4];
      unsigned long long* dst =
          (unsigned long long*)(y + ((size_t)r * SS + t) * 1024 + dir * HH + wg * 16 + seg * 4);
      __hip_atomic_store(dst, hv8, __ATOMIC_RELAXED, __HIP_MEMORY_SCOPE_AGENT);
    }
    __atomic_signal_fence(__ATOMIC_RELEASE);
    __syncthreads();  // B4: storing waves' vmcnt drained before signal
    if (tid == 0)
      __hip_atomic_store(&fl[wg * FPAD], s + 1, __ATOMIC_RELAXED, __HIP_MEMORY_SCOPE_AGENT);
  }
}

// ---------------- launch ----------------
extern "C" void kernel_launch(void* const* d_in, const int* in_sizes, int n_in,
                              void* d_out, int out_size, void* d_ws, size_t ws_size,
                              hipStream_t stream) {
  (void)in_sizes; (void)n_in; (void)out_size; (void)ws_size;
  const float* x = (const float*)d_in[0];
  const float* Wih[4] = {(const float*)d_in[1], (const float*)d_in[5],
                         (const float*)d_in[9], (const float*)d_in[13]};
  const float* Whh[4] = {(const float*)d_in[2], (const float*)d_in[6],
                         (const float*)d_in[10], (const float*)d_in[14]};
  const float* bih[4] = {(const float*)d_in[3], (const float*)d_in[7],
                         (const float*)d_in[11], (const float*)d_in[15]};
  const float* bhh[4] = {(const float*)d_in[4], (const float*)d_in[8],
                         (const float*)d_in[12], (const float*)d_in[16]};

  char* p = (char*)d_ws;
  auto take = [&](size_t bytes) { char* r = p; p += (bytes + 255) & ~(size_t)255; return r; };
  _Float16* x16  = (_Float16*)take((size_t)BB * SS * 512 * 2);
  _Float16* wih0 = (_Float16*)take((size_t)2 * G4 * 512 * 2);
  _Float16* wih1 = (_Float16*)take((size_t)2 * G4 * 1024 * 2);
  _Float16* whh16 = (_Float16*)take((size_t)4 * G4 * 512 * 2);
  _Float16* gx   = (_Float16*)take((size_t)2 * SS * BB * G4 * 2);
  _Float16* y0   = (_Float16*)take((size_t)BB * SS * 1024 * 2);
  _Float16* y1   = (_Float16*)take((size_t)BB * SS * 1024 * 2);
  int* flags     = (int*)take((size_t)2 * 2 * NWGR * FPAD * 4);  // 2 layers x 2 dirs

  hipLaunchKernelGGL(k_zero, dim3(8), dim3(256), 0, stream, flags, 2 * 2 * NWGR * FPAD);
  hipLaunchKernelGGL(k_cvt, dim3(512), dim3(256), 0, stream, x, x16, BB * SS * 512);
  hipLaunchKernelGGL(k_cvt, dim3(128), dim3(256), 0, stream, Wih[0], wih0, G4 * 512);
  hipLaunchKernelGGL(k_cvt, dim3(128), dim3(256), 0, stream, Wih[1], wih0 + (size_t)G4 * 512, G4 * 512);
  hipLaunchKernelGGL(k_cvt, dim3(256), dim3(256), 0, stream, Wih[2], wih1, G4 * 1024);
  hipLaunchKernelGGL(k_cvt, dim3(256), dim3(256), 0, stream, Wih[3], wih1 + (size_t)G4 * 1024, G4 * 1024);
  for (int i = 0; i < 4; ++i)
    hipLaunchKernelGGL(k_cvt, dim3(128), dim3(256), 0, stream, Whh[i],
                       whh16 + (size_t)i * G4 * 512, G4 * 512);

  // layer 0
  hipLaunchKernelGGL(k_gemm, dim3(128, 16, 2), dim3(256), 0, stream,
                     x16, wih0, bih[0], bhh[0], bih[1], bhh[1], gx, 512);
  {
    const _Float16* gxp = gx; const _Float16* whhp = whh16;
    _Float16* yp = y0; float* op = nullptr; int* cp = flags;
    void* args[] = {&gxp, &whhp, &yp, &op, &cp};
    hipLaunchCooperativeKernel((const void*)k_recur, dim3(2 * NWGR), dim3(512), args, 0, stream);
  }
  // layer 1
  hipLaunchKernelGGL(k_gemm, dim3(128, 16, 2), dim3(256), 0, stream,
                     y0, wih1, bih[2], bhh[2], bih[3], bhh[3], gx, 1024);
  {
    const _Float16* gxp = gx; const _Float16* whhp = whh16 + (size_t)2 * G4 * 512;
    _Float16* yp = y1; float* op = (float*)d_out; int* cp = flags + 2 * NWGR * FPAD;
    void* args[] = {&gxp, &whhp, &yp, &op, &cp};
    hipLaunchCooperativeKernel((const void*)k_recur, dim3(2 * NWGR), dim3(512), args, 0, stream);
  }
}

// Round 7
// 4205.858 us; speedup vs baseline: 3.9844x; 1.0262x over previous
//
#include <hip/hip_runtime.h>
#include <hip/hip_fp16.h>

typedef _Float16 f16x8 __attribute__((ext_vector_type(8)));
typedef float f32x4 __attribute__((ext_vector_type(4)));

namespace {
constexpr int BB = 32;    // batch
constexpr int SS = 512;   // seq len
constexpr int HH = 512;   // hidden
constexpr int G4 = 2048;  // 4*H gates
constexpr int NWGR = 32;  // workgroups per direction in recurrence (512 thr each)
constexpr int FPAD = 16;  // flag padding: 16 ints = 64B line per flag
}

// ---------------- utility kernels ----------------
__global__ void k_zero(int* __restrict__ p, int n) {
  int i = blockIdx.x * blockDim.x + threadIdx.x;
  if (i < n) p[i] = 0;
}

__global__ void k_cvt(const float* __restrict__ s, _Float16* __restrict__ d, int n) {
  int i = blockIdx.x * blockDim.x + threadIdx.x;
  int stride = gridDim.x * blockDim.x;
  for (; i < n; i += stride) d[i] = (_Float16)s[i];
}

// ---------------- input-projection GEMM (unchanged, proven R1-R4) ----------------
__global__ __launch_bounds__(256) void k_gemm(
    const _Float16* __restrict__ Ain,  // [16384][K]
    const _Float16* __restrict__ W,    // [2][2048][K]
    const float* __restrict__ bih0, const float* __restrict__ bhh0,
    const float* __restrict__ bih1, const float* __restrict__ bhh1,
    _Float16* __restrict__ gx,         // [2][512][32][2048]
    int K) {
  __shared__ _Float16 As[128][40];
  __shared__ _Float16 Bs[128][40];
  const int tid = threadIdx.x;
  const int lane = tid & 63, wave = tid >> 6;
  const int dir = blockIdx.z;
  const int r0 = blockIdx.x * 128;
  const int n0 = blockIdx.y * 128;
  const _Float16* Wd = W + (size_t)dir * G4 * K;
  const float* bi = dir ? bih1 : bih0;
  const float* bh = dir ? bhh1 : bhh0;
  const int mw = wave & 1, nw = wave >> 1;

  f32x4 acc[4][4];
#pragma unroll
  for (int a = 0; a < 4; ++a)
#pragma unroll
    for (int b = 0; b < 4; ++b) acc[a][b] = (f32x4){0.f, 0.f, 0.f, 0.f};

  const int c1 = tid, c2 = tid + 256;
  const int ar1 = c1 >> 2, ak1 = (c1 & 3) * 8;
  const int ar2 = c2 >> 2, ak2 = (c2 & 3) * 8;
  const int fr = lane & 15, fq = (lane >> 4) * 8;

  const int nstage = K >> 5;
  for (int ks = 0; ks < nstage; ++ks) {
    const int k0 = ks << 5;
    *(f16x8*)&As[ar1][ak1] = *(const f16x8*)&Ain[(size_t)(r0 + ar1) * K + k0 + ak1];
    *(f16x8*)&As[ar2][ak2] = *(const f16x8*)&Ain[(size_t)(r0 + ar2) * K + k0 + ak2];
    *(f16x8*)&Bs[ar1][ak1] = *(const f16x8*)&Wd[(size_t)(n0 + ar1) * K + k0 + ak1];
    *(f16x8*)&Bs[ar2][ak2] = *(const f16x8*)&Wd[(size_t)(n0 + ar2) * K + k0 + ak2];
    __syncthreads();
    f16x8 af[4], bf[4];
#pragma unroll
    for (int mt = 0; mt < 4; ++mt) af[mt] = *(const f16x8*)&As[mw * 64 + mt * 16 + fr][fq];
#pragma unroll
    for (int nt = 0; nt < 4; ++nt) bf[nt] = *(const f16x8*)&Bs[nw * 64 + nt * 16 + fr][fq];
#pragma unroll
    for (int mt = 0; mt < 4; ++mt)
#pragma unroll
      for (int nt = 0; nt < 4; ++nt)
        acc[mt][nt] = __builtin_amdgcn_mfma_f32_16x16x32_f16(af[mt], bf[nt], acc[mt][nt], 0, 0, 0);
    __syncthreads();
  }

  const int q4 = (lane >> 4) * 4;
#pragma unroll
  for (int nt = 0; nt < 4; ++nt) {
    const int col = n0 + nw * 64 + nt * 16 + fr;
    const float bsum = bi[col] + bh[col];
#pragma unroll
    for (int mt = 0; mt < 4; ++mt) {
#pragma unroll
      for (int q = 0; q < 4; ++q) {
        const int r = r0 + mw * 64 + mt * 16 + q4 + q;
        const int b = r >> 9, t = r & 511;
        gx[(((size_t)dir * SS + t) * BB + b) * G4 + col] = (_Float16)(acc[mt][nt][q] + bsum);
      }
    }
  }
}

// ---------------- fast activations ----------------
__device__ __forceinline__ float sigmoid_fast(float x) {
  return __fdividef(1.f, 1.f + __expf(-x));
}
__device__ __forceinline__ float tanh_fast(float x) {
  const float e = __expf(2.f * x);
  return 1.f - __fdividef(2.f, e + 1.f);
}

// ---------------- recurrence: 64 WGs = 32 x 512thr per direction ----------------
// R4-proven agent-scope (L3) protocol, plain HIP only. Changes vs R4:
//  * per-wave polling of ONLY the 8 producers feeding this wave's K-chunk
//    (skew overlap; removes the post-poll barrier)
//  * h packed via 4-lane shuffles, no h_s LDS (removes one barrier)
//  * launch_bounds(512,1): VGPR cap 512 so bfrag[4][4] (64 VGPRs of Whh)
//    stays register-resident instead of being re-fetched each step
//  * outf (fp32 layer-1 out) stored after the signal, off the critical path
__global__ __launch_bounds__(512, 1) void k_recur(
    const _Float16* __restrict__ gx,   // [2][512][32][2048]
    const _Float16* __restrict__ Whh,  // [2][2048][512] fp16, this layer
    _Float16* __restrict__ y,          // [32][512][1024] fp16 layer output
    float* __restrict__ outf,          // nullptr, or [32][512][1024] fp32 (layer 1)
    int* __restrict__ flags) {         // [2][NWGR*FPAD]
  const int tid = threadIdx.x;
  const int lane = tid & 63, wave = tid >> 6;   // wave 0..7
  const int wg = blockIdx.x & (NWGR - 1);
  const int dir = blockIdx.x >> 5;
  const int m = wave & 1, kc = wave >> 1;       // batch half, K chunk

  __shared__ float gp_s[16][32][18];            // [kc*4+gate][batch][unit] partials

  const int c = lane & 15;
  const int qd = lane >> 4;
  const int quad8 = qd * 8;

  // B-frags: gate row = g*512 + wg*16 + c, k = kc*128 + kj*32 + quad8
  const _Float16* WdB = Whh + (size_t)dir * G4 * HH;
  f16x8 bfrag[4][4];
#pragma unroll
  for (int g = 0; g < 4; ++g)
#pragma unroll
    for (int kj = 0; kj < 4; ++kj)
      bfrag[g][kj] =
          *(const f16x8*)&WdB[(size_t)(g * HH + wg * 16 + c) * HH + kc * 128 + kj * 32 + quad8];

  const int tb = tid >> 4, tu = tid & 15;  // pointwise ownership (batch, unit)
  float cstate = 0.f;

  const _Float16* gxd = gx + (size_t)dir * SS * BB * G4;
  int* fl = flags + dir * (NWGR * FPAD);
  // this wave's K-chunk [kc*128, kc*128+128) is produced by WGs kc*8 .. kc*8+7
  const int myprod = kc * 8 + (lane & 7);

  struct U2 { unsigned long long a, b; };

  for (int s = 0; s < SS; ++s) {
    const int t = dir ? (SS - 1 - s) : s;
    const int tprev = dir ? (t + 1) : (t - 1);

    // gx prefetch (plain cached loads; overlaps the wait)
    const _Float16* gq = gxd + ((size_t)t * BB + tb) * G4 + wg * 16 + tu;
    const float gxi = (float)gq[0];
    const float gxf = (float)gq[HH];
    const float gxg = (float)gq[2 * HH];
    const float gxo = (float)gq[3 * HH];

    f32x4 acc[4];
#pragma unroll
    for (int g = 0; g < 4; ++g) acc[g] = (f32x4){0.f, 0.f, 0.f, 0.f};

    if (s > 0) {
      // per-wave poll: lanes 0..7 each watch one of this wave's 8 producers
      while (true) {
        int v = s;
        if (lane < 8)
          v = __hip_atomic_load(&fl[myprod * FPAD], __ATOMIC_RELAXED, __HIP_MEMORY_SCOPE_AGENT);
        if (__all(v >= s)) break;
        __builtin_amdgcn_s_sleep(1);
      }
      __atomic_signal_fence(__ATOMIC_ACQUIRE);
      // A-frags: batch row = m*16 + c, this wave's disjoint 128-wide K chunk
      const _Float16* hrow = y + ((size_t)(m * 16 + c) * SS + tprev) * 1024 + dir * HH;
      const unsigned long long* h64 = (const unsigned long long*)hrow;
      f16x8 af[4];
#pragma unroll
      for (int kj = 0; kj < 4; ++kj) {
        const int o = kc * 32 + kj * 8 + qd * 2;
        U2 u;
        u.a = __hip_atomic_load(h64 + o, __ATOMIC_RELAXED, __HIP_MEMORY_SCOPE_AGENT);
        u.b = __hip_atomic_load(h64 + o + 1, __ATOMIC_RELAXED, __HIP_MEMORY_SCOPE_AGENT);
        af[kj] = __builtin_bit_cast(f16x8, u);
      }
#pragma unroll
      for (int kj = 0; kj < 4; ++kj)
#pragma unroll
        for (int g = 0; g < 4; ++g)
          acc[g] = __builtin_amdgcn_mfma_f32_16x16x32_f16(af[kj], bfrag[g][kj], acc[g], 0, 0, 0);
    }
    // scatter partials: D col = lane&15 (unit), row = qd*4+q (batch)
#pragma unroll
    for (int g = 0; g < 4; ++g)
#pragma unroll
      for (int q = 0; q < 4; ++q) gp_s[kc * 4 + g][m * 16 + qd * 4 + q][c] = acc[g][q];
    __syncthreads();  // B2: all waves' partials in LDS

    // pointwise: thread (tb, tu) reduces 4 K-chunk partials per gate
    const float ip = gp_s[0][tb][tu] + gp_s[4][tb][tu] + gp_s[8][tb][tu] + gp_s[12][tb][tu] + gxi;
    const float fp = gp_s[1][tb][tu] + gp_s[5][tb][tu] + gp_s[9][tb][tu] + gp_s[13][tb][tu] + gxf;
    const float gp = gp_s[2][tb][tu] + gp_s[6][tb][tu] + gp_s[10][tb][tu] + gp_s[14][tb][tu] + gxg;
    const float op = gp_s[3][tb][tu] + gp_s[7][tb][tu] + gp_s[11][tb][tu] + gp_s[15][tb][tu] + gxo;
    const float iv = sigmoid_fast(ip);
    const float fv = sigmoid_fast(fp);
    const float gv = tanh_fast(gp);
    const float ov = sigmoid_fast(op);
    cstate = fv * cstate + iv * gv;
    const float hv = ov * tanh_fast(cstate);

    // pack 4 lanes' fp16 h into one 8B value via shuffles (no LDS round trip).
    // lanes l..l+3 (l%4==0) hold units tu..tu+3 of batch tb (16 | 4: no straddle).
    const unsigned hb = (unsigned)__builtin_bit_cast(unsigned short, (_Float16)hv);
    const unsigned pair = hb | (__shfl_down(hb, 1) << 16);
    const unsigned long long quad =
        (unsigned long long)pair | ((unsigned long long)__shfl_down(pair, 2) << 32);
    if ((lane & 3) == 0) {
      unsigned long long* dst =
          (unsigned long long*)(y + ((size_t)tb * SS + t) * 1024 + dir * HH + wg * 16 + tu);
      __hip_atomic_store(dst, quad, __ATOMIC_RELAXED, __HIP_MEMORY_SCOPE_AGENT);
    }
    __atomic_signal_fence(__ATOMIC_RELEASE);
    __syncthreads();  // B4: every wave's h stores vmcnt-drained before the signal
    if (tid == 0)
      __hip_atomic_store(&fl[wg * FPAD], s + 1, __ATOMIC_RELAXED, __HIP_MEMORY_SCOPE_AGENT);
    // fp32 layer-1 output: after the signal, off the critical path
    if (outf) outf[((size_t)tb * SS + t) * 1024 + dir * HH + wg * 16 + tu] = hv;
  }
}

// ---------------- launch ----------------
extern "C" void kernel_launch(void* const* d_in, const int* in_sizes, int n_in,
                              void* d_out, int out_size, void* d_ws, size_t ws_size,
                              hipStream_t stream) {
  (void)in_sizes; (void)n_in; (void)out_size; (void)ws_size;
  const float* x = (const float*)d_in[0];
  const float* Wih[4] = {(const float*)d_in[1], (const float*)d_in[5],
                         (const float*)d_in[9], (const float*)d_in[13]};
  const float* Whh[4] = {(const float*)d_in[2], (const float*)d_in[6],
                         (const float*)d_in[10], (const float*)d_in[14]};
  const float* bih[4] = {(const float*)d_in[3], (const float*)d_in[7],
                         (const float*)d_in[11], (const float*)d_in[15]};
  const float* bhh[4] = {(const float*)d_in[4], (const float*)d_in[8],
                         (const float*)d_in[12], (const float*)d_in[16]};

  char* p = (char*)d_ws;
  auto take = [&](size_t bytes) { char* r = p; p += (bytes + 255) & ~(size_t)255; return r; };
  _Float16* x16  = (_Float16*)take((size_t)BB * SS * 512 * 2);
  _Float16* wih0 = (_Float16*)take((size_t)2 * G4 * 512 * 2);
  _Float16* wih1 = (_Float16*)take((size_t)2 * G4 * 1024 * 2);
  _Float16* whh16 = (_Float16*)take((size_t)4 * G4 * 512 * 2);
  _Float16* gx   = (_Float16*)take((size_t)2 * SS * BB * G4 * 2);
  _Float16* y0   = (_Float16*)take((size_t)BB * SS * 1024 * 2);
  _Float16* y1   = (_Float16*)take((size_t)BB * SS * 1024 * 2);
  int* flags     = (int*)take((size_t)2 * 2 * NWGR * FPAD * 4);  // 2 layers x 2 dirs

  hipLaunchKernelGGL(k_zero, dim3(8), dim3(256), 0, stream, flags, 2 * 2 * NWGR * FPAD);
  hipLaunchKernelGGL(k_cvt, dim3(512), dim3(256), 0, stream, x, x16, BB * SS * 512);
  hipLaunchKernelGGL(k_cvt, dim3(128), dim3(256), 0, stream, Wih[0], wih0, G4 * 512);
  hipLaunchKernelGGL(k_cvt, dim3(128), dim3(256), 0, stream, Wih[1], wih0 + (size_t)G4 * 512, G4 * 512);
  hipLaunchKernelGGL(k_cvt, dim3(256), dim3(256), 0, stream, Wih[2], wih1, G4 * 1024);
  hipLaunchKernelGGL(k_cvt, dim3(256), dim3(256), 0, stream, Wih[3], wih1 + (size_t)G4 * 1024, G4 * 1024);
  for (int i = 0; i < 4; ++i)
    hipLaunchKernelGGL(k_cvt, dim3(128), dim3(256), 0, stream, Whh[i],
                       whh16 + (size_t)i * G4 * 512, G4 * 512);

  // layer 0
  hipLaunchKernelGGL(k_gemm, dim3(128, 16, 2), dim3(256), 0, stream,
                     x16, wih0, bih[0], bhh[0], bih[1], bhh[1], gx, 512);
  {
    const _Float16* gxp = gx; const _Float16* whhp = whh16;
    _Float16* yp = y0; float* op = nullptr; int* cp = flags;
    void* args[] = {&gxp, &whhp, &yp, &op, &cp};
    hipLaunchCooperativeKernel((const void*)k_recur, dim3(2 * NWGR), dim3(512), args, 0, stream);
  }
  // layer 1
  hipLaunchKernelGGL(k_gemm, dim3(128, 16, 2), dim3(256), 0, stream,
                     y0, wih1, bih[2], bhh[2], bih[3], bhh[3], gx, 1024);
  {
    const _Float16* gxp = gx; const _Float16* whhp = whh16 + (size_t)2 * G4 * 512;
    _Float16* yp = y1; float* op = (float*)d_out; int* cp = flags + 2 * NWGR * FPAD;
    void* args[] = {&gxp, &whhp, &yp, &op, &cp};
    hipLaunchCooperativeKernel((const void*)k_recur, dim3(2 * NWGR), dim3(512), args, 0, stream);
  }
}